// Round 10
// baseline (101.378 us; speedup 1.0000x reference)
//
#include <hip/hip_runtime.h>
#include <cstdint>
#include <cmath>

#define Bb   128
#define INN  1024
#define OUTN 1024
#define A_TOT   (0.005f / 128.0f)   // fold mean-over-B (exact /2^7) into amplitude
#define INV_TAU (1.0f / 20.0f)

// round-to-nearest-even f32 -> bf16 (as uint16 in low bits)
__device__ __forceinline__ uint32_t rne_bf16(float f) {
    uint32_t u = __float_as_uint(f);
    return (u + 0x7fffu + ((u >> 16) & 1u)) >> 16;
}

// ---------------------------------------------------------------------------
// 1) prep: W transpose + IPackT + spike compaction (unchanged from R9).
//    IPackT[i*B + b] = (bf16(Iz)<<16) | bf16(Iy), Iz=e^{-dp/tau},
//    Iy=A*e^{dp/tau}.  b-minor layout so stdp stages it b128-wise.
// ---------------------------------------------------------------------------
__global__ __launch_bounds__(256) void prep_k(
    const float* __restrict__ W, const float* __restrict__ in_spikes,
    const float* __restrict__ delta_pre,
    float* __restrict__ Wt, uint32_t* __restrict__ IPackT,
    int* __restrict__ gIdx, int* __restrict__ gCount) {
    __shared__ float tile[32][33];
    const int blk = blockIdx.x;           // 0..511
    const int t   = threadIdx.x;

    // spike compaction (ballot order: deterministic across replays)
    if ((blk & 3) == 0 && t < 64) {
        const int b = blk >> 2;
        int base = 0;
#pragma unroll
        for (int c = 0; c < 16; c++) {
            float s = in_spikes[(size_t)b * INN + c * 64 + t];
            unsigned long long m = __ballot(s > 0.0f);
            if (s > 0.0f) {
                int pos = base + __popcll(m & ((1ULL << t) - 1ULL));
                gIdx[b * INN + pos] = c * 64 + t;
            }
            base += __popcll(m);
        }
        if (t == 0) gCount[b] = base;
    }

    // IPackT: one (b,i) entry per thread; coalesced read, scattered store
    {
        const int e = blk * 256 + t;      // 0..131071
        const int b = e >> 10, i = e & 1023;
        float sp = in_spikes[e];
        float dp = (sp > 0.0f) ? 0.0f : delta_pre[e] + 1.0f;
        float Iz = expf(-dp * INV_TAU);
        float Iy = A_TOT * expf(dp * INV_TAU);
        IPackT[(size_t)i * Bb + b] = (rne_bf16(Iz) << 16) | rne_bf16(Iy);
    }

    // transpose: two 32x32 tiles per block
    const int x = t & 31, y = t >> 5;
#pragma unroll
    for (int k = 0; k < 2; k++) {
        int tau = blk * 2 + k;
        int bx = tau & 31, by = tau >> 5;     // bx: i-tile, by: o-tile
        __syncthreads();
#pragma unroll
        for (int j = 0; j < 4; j++)
            tile[y + j * 8][x] = W[(size_t)(by * 32 + y + j * 8) * INN + bx * 32 + x];
        __syncthreads();
#pragma unroll
        for (int j = 0; j < 4; j++)
            Wt[(size_t)(bx * 32 + y + j * 8) * OUTN + by * 32 + x] = tile[x][y + j * 8];
    }
}

// ---------------------------------------------------------------------------
// 2) sparse projection + LIF + OPackT (b-minor, unchanged from R9).
//    OPackT[o*B + b] = (bf16(Oy)<<16) | bf16(Oz), Oy=e^{-df/tau},
//    Oz=-A*e^{df/tau}.
// ---------------------------------------------------------------------------
__global__ __launch_bounds__(256) void spmv_lif_k(
    const float* __restrict__ Wt, const float* __restrict__ membrane,
    const float* __restrict__ delta_fire,
    const int* __restrict__ gIdx, const int* __restrict__ gCount,
    uint32_t* __restrict__ OPackT,
    float* __restrict__ out_spike, float* __restrict__ out_mem) {
    __shared__ int sIdx[INN];
    const int b = blockIdx.x;
    const int z = blockIdx.y;
    const int t = threadIdx.x;
    const int n = gCount[b];
    for (int j = t; j < n; j += 256) sIdx[j] = gIdx[b * INN + j];
    __syncthreads();

    const int o = z * 256 + t;
    float acc = 0.0f;
    int j = 0;
    for (; j + 8 <= n; j += 8) {            // 8 loads in flight
        float w0 = Wt[(size_t)sIdx[j + 0] * OUTN + o];
        float w1 = Wt[(size_t)sIdx[j + 1] * OUTN + o];
        float w2 = Wt[(size_t)sIdx[j + 2] * OUTN + o];
        float w3 = Wt[(size_t)sIdx[j + 3] * OUTN + o];
        float w4 = Wt[(size_t)sIdx[j + 4] * OUTN + o];
        float w5 = Wt[(size_t)sIdx[j + 5] * OUTN + o];
        float w6 = Wt[(size_t)sIdx[j + 6] * OUTN + o];
        float w7 = Wt[(size_t)sIdx[j + 7] * OUTN + o];
        acc += ((w0 + w1) + (w2 + w3)) + ((w4 + w5) + (w6 + w7));
    }
    for (; j < n; j++) acc += Wt[(size_t)sIdx[j] * OUTN + o];

    const int n_bo = b * OUTN + o;
    float mem = membrane[n_bo] * 0.99f + acc;
    float s = (mem > 1.0f) ? 1.0f : 0.0f;
    mem = (s > 0.0f) ? mem - 0.8f : mem;
    out_spike[n_bo] = s;
    out_mem[n_bo] = mem;

    float df = (s > 0.0f) ? 0.0f : delta_fire[n_bo] + 1.0f;
    float Oy = expf(-df * INV_TAU);
    float Oz = -A_TOT * expf(df * INV_TAU);
    OPackT[(size_t)o * Bb + b] = (rne_bf16(Oy) << 16) | rne_bf16(Oz);
}

// ---------------------------------------------------------------------------
// 3) STDP, wave-split-B: grid 256 x 256 (1 block/CU). Block = 64x64 tile;
//    each of the 4 waves covers the FULL tile (8x8 micro, 64 acc) for its
//    own B-quarter (32 b) -> zero inner barriers, VALU-bound solo-SIMD
//    stream (16 ds_read_b128 per 1024 VALU ops per 4-b step). LDS columns
//    XOR-swizzled by (row>>3) -> reads hit 8 distinct bank-quads.
//    Epilogue: all waves dump partials (64 KB LDS reuse), flat re-map for
//    coalesced combine with W.
//      min_u32(pO,pI) = selected key, max_u32(pO,pI)<<16 = selected payload.
// ---------------------------------------------------------------------------
__global__ __launch_bounds__(256, 1) void stdp_k(
    const float* __restrict__ W, const uint32_t* __restrict__ OPackT,
    const uint32_t* __restrict__ IPackT, float* __restrict__ outW) {
    __shared__ uint32_t sm[16384];       // 64 KB: staging, then partial dump
    uint32_t* sOT = sm;                  // [64][128] o-major, b-minor, swz
    uint32_t* sIT = sm + 8192;           // [64][128] i-major, b-minor, swz
    const int t    = threadIdx.x;
    const int lane = t & 63, q = t >> 6;       // q = wave = B-quarter
    const int ly = lane >> 3, lx = lane & 7;   // o = 8*ly + a, i = 8*lx + c
    const int o0 = (blockIdx.x & 15) * 64;
    const int i0 = (blockIdx.x >> 4) * 64;

    // stage all 128 b for both arrays: 4096 uint4 / 256 threads = 16 each
#pragma unroll
    for (int r = 0; r < 8; r++) {
        const int idx = r * 256 + t;           // 0..2047
        const int row = idx >> 5, c = idx & 31;
        const int cs = (c ^ (row >> 3)) << 2;  // bank-quad permutation
        *(uint4*)&sOT[row * 128 + cs] =
            *(const uint4*)&OPackT[(size_t)(o0 + row) * Bb + c * 4];
        *(uint4*)&sIT[row * 128 + cs] =
            *(const uint4*)&IPackT[(size_t)(i0 + row) * Bb + c * 4];
    }
    __syncthreads();

    float acc[8][8];
#pragma unroll
    for (int a = 0; a < 8; a++)
#pragma unroll
        for (int c = 0; c < 8; c++) acc[a][c] = 0.0f;

#pragma unroll 2
    for (int s = 0; s < 8; s++) {              // 4 b's per step, 32 b total
        const int cq = q * 8 + s;              // this wave's b-chunk (0..31)
        uint4 ov[8], iv[8];
#pragma unroll
        for (int a = 0; a < 8; a++)
            ov[a] = *(const uint4*)&sOT[(8 * ly + a) * 128 + ((cq ^ ly) << 2)];
#pragma unroll
        for (int c = 0; c < 8; c++)
            iv[c] = *(const uint4*)&sIT[(8 * lx + c) * 128 + ((cq ^ lx) << 2)];
#pragma unroll
        for (int a = 0; a < 8; a++) {
            const uint32_t oo[4] = {ov[a].x, ov[a].y, ov[a].z, ov[a].w};
#pragma unroll
            for (int c = 0; c < 8; c++) {
                const uint32_t ii[4] = {iv[c].x, iv[c].y, iv[c].z, iv[c].w};
#pragma unroll
                for (int k = 0; k < 4; k++) {
                    uint32_t kk = min(oo[k], ii[k]);
                    uint32_t pp = max(oo[k], ii[k]) << 16;
                    acc[a][c] = fmaf(__uint_as_float(kk),
                                     __uint_as_float(pp), acc[a][c]);
                }
            }
        }
    }
    __syncthreads();

    // dump partials: epi[q][o_local*64 + i_local], 2 float4 per a
    float* epi = (float*)sm;                   // [4][4096]
#pragma unroll
    for (int a = 0; a < 8; a++) {
        const int base = q * 4096 + (8 * ly + a) * 64 + 8 * lx;
        *(float4*)&epi[base]     = make_float4(acc[a][0], acc[a][1],
                                               acc[a][2], acc[a][3]);
        *(float4*)&epi[base + 4] = make_float4(acc[a][4], acc[a][5],
                                               acc[a][6], acc[a][7]);
    }
    __syncthreads();

    // combine 4 partials + W, flat re-map: wave-instr = one o-row, i = lane
    // -> perfectly coalesced global access.
#pragma unroll
    for (int j = 0; j < 16; j++) {
        const int flat = j * 256 + t;          // 0..4095
        const int ol = flat >> 6, il = flat & 63;
        float v = (epi[flat] + epi[flat + 4096]) +
                  (epi[flat + 8192] + epi[flat + 12288]);
        const size_t off = (size_t)(o0 + ol) * INN + i0 + il;
        outW[off] = W[off] + v;
    }
}

// ---------------------------------------------------------------------------
extern "C" void kernel_launch(void* const* d_in, const int* in_sizes, int n_in,
                              void* d_out, int out_size, void* d_ws, size_t ws_size,
                              hipStream_t stream) {
    const float* in_spikes  = (const float*)d_in[0];
    const float* W          = (const float*)d_in[1];
    const float* membrane   = (const float*)d_in[2];
    const float* delta_pre  = (const float*)d_in[3];
    const float* delta_fire = (const float*)d_in[4];

    float* out_spike = (float*)d_out;                       // (B,OUT)
    float* out_W     = out_spike + (size_t)Bb * OUTN;       // (OUT,IN)
    float* out_mem   = out_W + (size_t)OUTN * INN;          // (B,OUT)

    float* ws        = (float*)d_ws;
    float* Wt        = ws;                                      // 4 MB
    uint32_t* OPackT = (uint32_t*)(Wt + (size_t)INN * OUTN);    // 512 KB
    uint32_t* IPackT = OPackT + (size_t)OUTN * Bb;              // 512 KB
    int* gIdx        = (int*)(IPackT + (size_t)INN * Bb);       // 512 KB
    int* gCount      = gIdx + (size_t)Bb * INN;                 // 512 B

    hipLaunchKernelGGL(prep_k, dim3(512), dim3(256), 0, stream,
                       W, in_spikes, delta_pre, Wt, IPackT, gIdx, gCount);
    hipLaunchKernelGGL(spmv_lif_k, dim3(Bb, 4), dim3(256), 0, stream,
                       Wt, membrane, delta_fire, gIdx, gCount,
                       OPackT, out_spike, out_mem);
    hipLaunchKernelGGL(stdp_k, dim3(256), dim3(256), 0, stream,
                       W, OPackT, IPackT, out_W);
}

// Round 11
// 100.064 us; speedup vs baseline: 1.0131x; 1.0131x over previous
//
#include <hip/hip_runtime.h>
#include <cstdint>
#include <cmath>

#define Bb   128
#define INN  1024
#define OUTN 1024
#define A_TOT   (0.005f / 128.0f)   // fold mean-over-B (exact /2^7) into amplitude
#define INV_TAU (1.0f / 20.0f)

// round-to-nearest-even f32 -> bf16 (as uint16 in low bits)
__device__ __forceinline__ uint32_t rne_bf16(float f) {
    uint32_t u = __float_as_uint(f);
    return (u + 0x7fffu + ((u >> 16) & 1u)) >> 16;
}

// ---------------------------------------------------------------------------
// 1) prep: W transpose + IPackT + spike compaction.
//    IPackT[i*B + b] = (bf16(Iz)<<16) | bf16(Iy), Iz=e^{-dp/tau},
//    Iy=A*e^{dp/tau}.  b-minor layout so stdp stages it b128-wise.
// ---------------------------------------------------------------------------
__global__ __launch_bounds__(256) void prep_k(
    const float* __restrict__ W, const float* __restrict__ in_spikes,
    const float* __restrict__ delta_pre,
    float* __restrict__ Wt, uint32_t* __restrict__ IPackT,
    int* __restrict__ gIdx, int* __restrict__ gCount) {
    __shared__ float tile[32][33];
    const int blk = blockIdx.x;           // 0..511
    const int t   = threadIdx.x;

    // spike compaction (ballot order: deterministic across replays)
    if ((blk & 3) == 0 && t < 64) {
        const int b = blk >> 2;
        int base = 0;
#pragma unroll
        for (int c = 0; c < 16; c++) {
            float s = in_spikes[(size_t)b * INN + c * 64 + t];
            unsigned long long m = __ballot(s > 0.0f);
            if (s > 0.0f) {
                int pos = base + __popcll(m & ((1ULL << t) - 1ULL));
                gIdx[b * INN + pos] = c * 64 + t;
            }
            base += __popcll(m);
        }
        if (t == 0) gCount[b] = base;
    }

    // IPackT: one (b,i) entry per thread; coalesced read, scattered store
    {
        const int e = blk * 256 + t;      // 0..131071
        const int b = e >> 10, i = e & 1023;
        float sp = in_spikes[e];
        float dp = (sp > 0.0f) ? 0.0f : delta_pre[e] + 1.0f;
        float Iz = expf(-dp * INV_TAU);
        float Iy = A_TOT * expf(dp * INV_TAU);
        IPackT[(size_t)i * Bb + b] = (rne_bf16(Iz) << 16) | rne_bf16(Iy);
    }

    // transpose: two 32x32 tiles per block
    const int x = t & 31, y = t >> 5;
#pragma unroll
    for (int k = 0; k < 2; k++) {
        int tau = blk * 2 + k;
        int bx = tau & 31, by = tau >> 5;     // bx: i-tile, by: o-tile
        __syncthreads();
#pragma unroll
        for (int j = 0; j < 4; j++)
            tile[y + j * 8][x] = W[(size_t)(by * 32 + y + j * 8) * INN + bx * 32 + x];
        __syncthreads();
#pragma unroll
        for (int j = 0; j < 4; j++)
            Wt[(size_t)(bx * 32 + y + j * 8) * OUTN + by * 32 + x] = tile[x][y + j * 8];
    }
}

// ---------------------------------------------------------------------------
// 2) sparse projection + LIF + OPackT (b-minor). grid (B,4), block (b,z)
//    covers o = z*256+t.
//    OPackT[o*B + b] = (bf16(Oy)<<16) | bf16(Oz), Oy=e^{-df/tau},
//    Oz=-A*e^{df/tau}.
// ---------------------------------------------------------------------------
__global__ __launch_bounds__(256) void spmv_lif_k(
    const float* __restrict__ Wt, const float* __restrict__ membrane,
    const float* __restrict__ delta_fire,
    const int* __restrict__ gIdx, const int* __restrict__ gCount,
    uint32_t* __restrict__ OPackT,
    float* __restrict__ out_spike, float* __restrict__ out_mem) {
    __shared__ int sIdx[INN];
    const int b = blockIdx.x;
    const int z = blockIdx.y;
    const int t = threadIdx.x;
    const int n = gCount[b];
    for (int j = t; j < n; j += 256) sIdx[j] = gIdx[b * INN + j];
    __syncthreads();

    const int o = z * 256 + t;
    float acc = 0.0f;
    int j = 0;
    for (; j + 8 <= n; j += 8) {            // 8 loads in flight
        float w0 = Wt[(size_t)sIdx[j + 0] * OUTN + o];
        float w1 = Wt[(size_t)sIdx[j + 1] * OUTN + o];
        float w2 = Wt[(size_t)sIdx[j + 2] * OUTN + o];
        float w3 = Wt[(size_t)sIdx[j + 3] * OUTN + o];
        float w4 = Wt[(size_t)sIdx[j + 4] * OUTN + o];
        float w5 = Wt[(size_t)sIdx[j + 5] * OUTN + o];
        float w6 = Wt[(size_t)sIdx[j + 6] * OUTN + o];
        float w7 = Wt[(size_t)sIdx[j + 7] * OUTN + o];
        acc += ((w0 + w1) + (w2 + w3)) + ((w4 + w5) + (w6 + w7));
    }
    for (; j < n; j++) acc += Wt[(size_t)sIdx[j] * OUTN + o];

    const int n_bo = b * OUTN + o;
    float mem = membrane[n_bo] * 0.99f + acc;
    float s = (mem > 1.0f) ? 1.0f : 0.0f;
    mem = (s > 0.0f) ? mem - 0.8f : mem;
    out_spike[n_bo] = s;
    out_mem[n_bo] = mem;

    float df = (s > 0.0f) ? 0.0f : delta_fire[n_bo] + 1.0f;
    float Oy = expf(-df * INV_TAU);
    float Oz = -A_TOT * expf(df * INV_TAU);
    OPackT[(size_t)o * Bb + b] = (rne_bf16(Oy) << 16) | rne_bf16(Oz);
}

// ---------------------------------------------------------------------------
// 3) STDP: new_W[o,i] = W[o,i] + sum_b sel(df>dp: Oy*Iy, df<dp: Oz*Iz)
//      min_u32(pO,pI) = selected key, max_u32(pO,pI)<<16 = selected payload.
//    32x32 tile, 2x2 micro, BOTH operands staged b-minor (sOT[o][b],
//    sIT[i][b]): per 4-b step 4 x b128 = 48 cyc / 16 products = 3.0
//    cyc/prod at 16 waves/CU (grid (32,32)=1024 blocks, 4 blk/CU). XOR
//    swizzle (chunk ^ ((row>>1)&7)) keeps staging a bank permutation and
//    reads <=2-way aliased (free, m136) while preserving 16-B alignment.
//    Best-measured stdp configuration (R9: 99.8 us total).
// ---------------------------------------------------------------------------
__global__ __launch_bounds__(256, 4) void stdp_k(
    const float* __restrict__ W, const uint32_t* __restrict__ OPackT,
    const uint32_t* __restrict__ IPackT, float* __restrict__ outW) {
    __shared__ uint32_t sOT[32 * 32];   // [o][b-chunk swz]  4 KB
    __shared__ uint32_t sIT[32 * 32];   // [i][b-chunk swz]  4 KB
    const int t  = threadIdx.x;
    const int o0 = blockIdx.x * 32;
    const int i0 = blockIdx.y * 32;
    const int tx = t & 15;              // i = i0 + 2*tx + {0,1}
    const int ty = t >> 4;              // o = o0 + 2*ty + {0,1}
    const int srow = t >> 3;            // staging row 0..31
    const int sc   = t & 7;             // staging b-chunk 0..7
    const int swr  = (srow >> 1) & 7;   // row swizzle key
    const int so = ty & 7, si = tx & 7; // read swizzle keys

    float acc[2][2] = {{0.f, 0.f}, {0.f, 0.f}};

    for (int cb = 0; cb < Bb / 32; cb++) {         // 4 chunks of 32 b
        const int b0 = cb * 32;
        // stage: one uint4 (4 b's) per array per thread, bank-permuted cols
        *(uint4*)&sOT[srow * 32 + ((sc ^ swr) << 2)] =
            *(const uint4*)&OPackT[(size_t)(o0 + srow) * Bb + b0 + 4 * sc];
        *(uint4*)&sIT[srow * 32 + ((sc ^ swr) << 2)] =
            *(const uint4*)&IPackT[(size_t)(i0 + srow) * Bb + b0 + 4 * sc];
        __syncthreads();

#pragma unroll
        for (int c4 = 0; c4 < 8; c4++) {           // 4 b's per step
            const int co = (c4 ^ so) << 2;
            const int ci = (c4 ^ si) << 2;
            uint4 oA = *(const uint4*)&sOT[(2 * ty + 0) * 32 + co];
            uint4 oB = *(const uint4*)&sOT[(2 * ty + 1) * 32 + co];
            uint4 iA = *(const uint4*)&sIT[(2 * tx + 0) * 32 + ci];
            uint4 iB = *(const uint4*)&sIT[(2 * tx + 1) * 32 + ci];
            const uint32_t ovA[4] = {oA.x, oA.y, oA.z, oA.w};
            const uint32_t ovB[4] = {oB.x, oB.y, oB.z, oB.w};
            const uint32_t ivA[4] = {iA.x, iA.y, iA.z, iA.w};
            const uint32_t ivB[4] = {iB.x, iB.y, iB.z, iB.w};
#pragma unroll
            for (int k = 0; k < 4; k++) {          // bb = b0 + 4*c4 + k
                uint32_t k00 = min(ovA[k], ivA[k]);
                uint32_t p00 = max(ovA[k], ivA[k]) << 16;
                acc[0][0] = fmaf(__uint_as_float(k00), __uint_as_float(p00),
                                 acc[0][0]);
                uint32_t k01 = min(ovA[k], ivB[k]);
                uint32_t p01 = max(ovA[k], ivB[k]) << 16;
                acc[0][1] = fmaf(__uint_as_float(k01), __uint_as_float(p01),
                                 acc[0][1]);
                uint32_t k10 = min(ovB[k], ivA[k]);
                uint32_t p10 = max(ovB[k], ivA[k]) << 16;
                acc[1][0] = fmaf(__uint_as_float(k10), __uint_as_float(p10),
                                 acc[1][0]);
                uint32_t k11 = min(ovB[k], ivB[k]);
                uint32_t p11 = max(ovB[k], ivB[k]) << 16;
                acc[1][1] = fmaf(__uint_as_float(k11), __uint_as_float(p11),
                                 acc[1][1]);
            }
        }
        __syncthreads();
    }

    // epilogue: new_W = W + acc  (float2 per (o, 2*tx))
#pragma unroll
    for (int a = 0; a < 2; a++) {
        const size_t off = (size_t)(o0 + 2 * ty + a) * INN + i0 + 2 * tx;
        float2 w = *(const float2*)&W[off];
        *(float2*)&outW[off] = make_float2(w.x + acc[a][0], w.y + acc[a][1]);
    }
}

// ---------------------------------------------------------------------------
extern "C" void kernel_launch(void* const* d_in, const int* in_sizes, int n_in,
                              void* d_out, int out_size, void* d_ws, size_t ws_size,
                              hipStream_t stream) {
    const float* in_spikes  = (const float*)d_in[0];
    const float* W          = (const float*)d_in[1];
    const float* membrane   = (const float*)d_in[2];
    const float* delta_pre  = (const float*)d_in[3];
    const float* delta_fire = (const float*)d_in[4];

    float* out_spike = (float*)d_out;                       // (B,OUT)
    float* out_W     = out_spike + (size_t)Bb * OUTN;       // (OUT,IN)
    float* out_mem   = out_W + (size_t)OUTN * INN;          // (B,OUT)

    float* ws        = (float*)d_ws;
    float* Wt        = ws;                                      // 4 MB
    uint32_t* OPackT = (uint32_t*)(Wt + (size_t)INN * OUTN);    // 512 KB
    uint32_t* IPackT = OPackT + (size_t)OUTN * Bb;              // 512 KB
    int* gIdx        = (int*)(IPackT + (size_t)INN * Bb);       // 512 KB
    int* gCount      = gIdx + (size_t)Bb * INN;                 // 512 B

    hipLaunchKernelGGL(prep_k, dim3(512), dim3(256), 0, stream,
                       W, in_spikes, delta_pre, Wt, IPackT, gIdx, gCount);
    hipLaunchKernelGGL(spmv_lif_k, dim3(Bb, 4), dim3(256), 0, stream,
                       Wt, membrane, delta_fire, gIdx, gCount,
                       OPackT, out_spike, out_mem);
    hipLaunchKernelGGL(stdp_k, dim3(OUTN / 32, INN / 32), dim3(256), 0, stream,
                       W, OPackT, IPackT, out_W);
}